// Round 3
// baseline (656.115 us; speedup 1.0000x reference)
//
#include <hip/hip_runtime.h>
#include <cstdint>
#include <cstddef>

// ---------------------------------------------------------------------------
// Problem constants
// ---------------------------------------------------------------------------
#define BB    8      // batch
#define NH    12     // heads
#define BH    96     // BB*NH
#define SS    1024   // image tokens (32x32)
#define QQ    2048   // text tokens
#define DD    64     // head dim
#define HID   768
#define EDGE  32
#define KPOOL 16
#define POOLED 17

typedef short bf16x8 __attribute__((ext_vector_type(8)));
typedef float f32x4  __attribute__((ext_vector_type(4)));

#define MFMA16(a, b, c) __builtin_amdgcn_mfma_f32_16x16x32_bf16((a), (b), (c), 0, 0, 0)

// scores computed in base-2: Q pre-scaled by log2(e)/8 so exp(s/8) == exp2(score2)
#define QSCALE 0.18033688011112042f

#if __has_builtin(__builtin_amdgcn_exp2f)
#define EXP2(x) __builtin_amdgcn_exp2f(x)
#else
#define EXP2(x) exp2f(x)
#endif

__device__ __forceinline__ short f2bf(float x) {
    unsigned u = __builtin_bit_cast(unsigned, x);
    u = u + 0x7fffu + ((u >> 16) & 1u);          // RNE
    return (short)(u >> 16);
}
__device__ __forceinline__ float bf2f(short h) {
    unsigned u = ((unsigned)(unsigned short)h) << 16;
    return __builtin_bit_cast(float, u);
}

// ---------------------------------------------------------------------------
// K0a: cast text -> Q split hi/lo bf16, layout [bh][q][hi 64 | lo 64]
// ---------------------------------------------------------------------------
__global__ __launch_bounds__(256) void k_castq(const float* __restrict__ txt,
                                               short* __restrict__ Qs) {
    int t = threadIdx.x;
    int row = blockIdx.x * 4 + (t >> 6);         // row = bh*2048 + q
    int d = t & 63;
    int bh = row >> 11, q = row & 2047;
    int b = bh / NH, h = bh - b * NH;
    float x = txt[((size_t)b * QQ + q) * HID + h * DD + d] * QSCALE;
    short hi = f2bf(x);
    short lo = f2bf(x - bf2f(hi));
    size_t base = (size_t)row * 128;
    Qs[base + d] = hi;
    Qs[base + 64 + d] = lo;
}

// K0b: cast image -> K split hi/lo bf16, layout [bh][s][hi 64 | lo 64]
__global__ __launch_bounds__(256) void k_castk(const float* __restrict__ img,
                                               short* __restrict__ Ks) {
    int t = threadIdx.x;
    int row = blockIdx.x * 4 + (t >> 6);         // row = bh*1024 + s
    int d = t & 63;
    int bh = row >> 10, s = row & 1023;
    int b = bh / NH, h = bh - b * NH;
    float x = img[((size_t)b * SS + s) * HID + h * DD + d];
    short hi = f2bf(x);
    short lo = f2bf(x - bf2f(hi));
    size_t base = (size_t)row * 128;
    Ks[base + d] = hi;
    Ks[base + 64 + d] = lo;
}

// K0c: W_in [k][n] -> transposed bf16 [n][k], LDS tile (coalesced both sides)
__global__ __launch_bounds__(256) void k_castw(const float* __restrict__ W,
                                               short* __restrict__ Wt) {
    __shared__ float T[64][65];
    int bx = blockIdx.x % 12, by = blockIdx.x / 12;
    for (int i = threadIdx.x; i < 4096; i += 256) {
        int r = i >> 6, cc = i & 63;
        T[r][cc] = W[(size_t)(by * 64 + r) * HID + bx * 64 + cc];
    }
    __syncthreads();
    for (int i = threadIdx.x; i < 4096; i += 256) {
        int r = i >> 6, cc = i & 63;             // r = n-local, cc = k-local
        Wt[(size_t)(bx * 64 + r) * HID + by * 64 + cc] = f2bf(T[cc][r]);
    }
}

// ---------------------------------------------------------------------------
// K1: Lsum[bh][q] = sum_s exp2(score2)  -- split-bf16 x3 MFMA, A=Q rows
// grid: bh * 16 qblk (128 q each); wave = 32 q rows, streams all 1024 s.
// Single writer per q: no memset, no atomics. Register prefetch distance 1.
// ---------------------------------------------------------------------------
__global__ __launch_bounds__(256, 4) void k_lsum(const short* __restrict__ Qs,
                                                 const short* __restrict__ Ks,
                                                 float* __restrict__ Lsum) {
    int qblk = blockIdx.x & 15;
    int bh = blockIdx.x >> 4;
    int wave = threadIdx.x >> 6, lane = threadIdx.x & 63;
    int quad = lane >> 4, c = lane & 15;
    int q0 = qblk * 128 + wave * 32;

    bf16x8 ahi0[2], ahi1[2], alo0[2], alo1[2];
#pragma unroll
    for (int t = 0; t < 2; t++) {
        const short* rp = Qs + ((size_t)bh * QQ + q0 + t * 16 + c) * 128 + quad * 8;
        ahi0[t] = *(const bf16x8*)(rp);
        ahi1[t] = *(const bf16x8*)(rp + 32);
        alo0[t] = *(const bf16x8*)(rp + 64);
        alo1[t] = *(const bf16x8*)(rp + 96);
    }
    f32x4 lacc[2];
    lacc[0] = (f32x4){0.f, 0.f, 0.f, 0.f};
    lacc[1] = (f32x4){0.f, 0.f, 0.f, 0.f};

    const short* bp = Ks + ((size_t)bh * SS + c) * 128 + quad * 8;
    bf16x8 nb0 = *(const bf16x8*)(bp);
    bf16x8 nb1 = *(const bf16x8*)(bp + 32);
    bf16x8 nb2 = *(const bf16x8*)(bp + 64);
    bf16x8 nb3 = *(const bf16x8*)(bp + 96);

    for (int s0 = 0; s0 < SS; s0 += 16) {
        bf16x8 b0 = nb0, b1 = nb1, b2 = nb2, b3 = nb3;
        bp += 16 * 128;
        // prefetch next chunk (last iter reads in-bounds scratch, unused)
        nb0 = *(const bf16x8*)(bp);
        nb1 = *(const bf16x8*)(bp + 32);
        nb2 = *(const bf16x8*)(bp + 64);
        nb3 = *(const bf16x8*)(bp + 96);
#pragma unroll
        for (int t = 0; t < 2; t++) {
            f32x4 acc = (f32x4){0.f, 0.f, 0.f, 0.f};
            acc = MFMA16(ahi0[t], b0, acc);
            acc = MFMA16(ahi1[t], b1, acc);
            acc = MFMA16(alo0[t], b0, acc);
            acc = MFMA16(alo1[t], b1, acc);
            acc = MFMA16(ahi0[t], b2, acc);
            acc = MFMA16(ahi1[t], b3, acc);
#pragma unroll
            for (int r = 0; r < 4; r++) lacc[t][r] += EXP2(acc[r]);
        }
    }
#pragma unroll
    for (int t = 0; t < 2; t++) {
#pragma unroll
        for (int r = 0; r < 4; r++) {
            float v = lacc[t][r];
            v += __shfl_xor(v, 1);
            v += __shfl_xor(v, 2);
            v += __shfl_xor(v, 4);
            v += __shfl_xor(v, 8);
            if (c == 0)
                Lsum[(size_t)bh * QQ + q0 + t * 16 + quad * 4 + r] = v;
        }
    }
}

// ---------------------------------------------------------------------------
// K2: image_attn[bh][s] += sum_q exp2(score2) / Lsum[q]   (A = K rows)
// grid: bh * 8 sblk (128 s) * 2 q-halves; wave = 32 s rows, streams 1024 q.
// ---------------------------------------------------------------------------
__global__ __launch_bounds__(256, 4) void k_attnacc(const short* __restrict__ Qs,
                                                    const short* __restrict__ Ks,
                                                    const float* __restrict__ Lsum,
                                                    float* __restrict__ iattn) {
    int qh = blockIdx.x & 1;
    int sblk = (blockIdx.x >> 1) & 7;
    int bh = blockIdx.x >> 4;
    int wave = threadIdx.x >> 6, lane = threadIdx.x & 63;
    int quad = lane >> 4, c = lane & 15;
    int s0w = sblk * 128 + wave * 32;

    bf16x8 ahi0[2], ahi1[2], alo0[2], alo1[2];
#pragma unroll
    for (int t = 0; t < 2; t++) {
        const short* rp = Ks + ((size_t)bh * SS + s0w + t * 16 + c) * 128 + quad * 8;
        ahi0[t] = *(const bf16x8*)(rp);
        ahi1[t] = *(const bf16x8*)(rp + 32);
        alo0[t] = *(const bf16x8*)(rp + 64);
        alo1[t] = *(const bf16x8*)(rp + 96);
    }
    f32x4 racc[2];
    racc[0] = (f32x4){0.f, 0.f, 0.f, 0.f};
    racc[1] = (f32x4){0.f, 0.f, 0.f, 0.f};

    const float* lbase = Lsum + (size_t)bh * QQ;
    int qstart = qh * 1024;
    const short* bp = Qs + ((size_t)bh * QQ + qstart + c) * 128 + quad * 8;
    bf16x8 nb0 = *(const bf16x8*)(bp);
    bf16x8 nb1 = *(const bf16x8*)(bp + 32);
    bf16x8 nb2 = *(const bf16x8*)(bp + 64);
    bf16x8 nb3 = *(const bf16x8*)(bp + 96);
    float rln = __builtin_amdgcn_rcpf(lbase[qstart + c]);

    for (int q0 = qstart; q0 < qstart + 1024; q0 += 16) {
        bf16x8 b0 = nb0, b1 = nb1, b2 = nb2, b3 = nb3;
        float rl = rln;
        bp += 16 * 128;
        nb0 = *(const bf16x8*)(bp);
        nb1 = *(const bf16x8*)(bp + 32);
        nb2 = *(const bf16x8*)(bp + 64);
        nb3 = *(const bf16x8*)(bp + 96);
        rln = __builtin_amdgcn_rcpf(lbase[q0 + 16 + c]);
#pragma unroll
        for (int t = 0; t < 2; t++) {
            f32x4 acc = (f32x4){0.f, 0.f, 0.f, 0.f};
            acc = MFMA16(ahi0[t], b0, acc);
            acc = MFMA16(ahi1[t], b1, acc);
            acc = MFMA16(alo0[t], b0, acc);
            acc = MFMA16(alo1[t], b1, acc);
            acc = MFMA16(ahi0[t], b2, acc);
            acc = MFMA16(ahi1[t], b3, acc);
#pragma unroll
            for (int r = 0; r < 4; r++)
                racc[t][r] = fmaf(EXP2(acc[r]), rl, racc[t][r]);
        }
    }
#pragma unroll
    for (int t = 0; t < 2; t++) {
#pragma unroll
        for (int r = 0; r < 4; r++) {
            float v = racc[t][r];
            v += __shfl_xor(v, 1);
            v += __shfl_xor(v, 2);
            v += __shfl_xor(v, 4);
            v += __shfl_xor(v, 8);
            if (c == 0)
                atomicAdd(&iattn[(size_t)bh * SS + s0w + t * 16 + quad * 4 + r], v);
        }
    }
}

// ---------------------------------------------------------------------------
// K3: 16x16 sum-pool (valid) over 32x32 map, argmax (np first-max tiebreak)
// ---------------------------------------------------------------------------
__global__ __launch_bounds__(256) void k_pool(const float* __restrict__ iattn,
                                              int* __restrict__ rc) {
    __shared__ float A[1024];
    __shared__ float V[POOLED * EDGE];
    __shared__ float bv[256];
    __shared__ int bi[256];
    int bh = blockIdx.x;
    for (int i = threadIdx.x; i < 1024; i += 256) A[i] = iattn[(size_t)bh * SS + i];
    __syncthreads();
    for (int i = threadIdx.x; i < POOLED * EDGE; i += 256) {
        int r = i >> 5, cc = i & 31;
        float s = 0.f;
#pragma unroll
        for (int k = 0; k < KPOOL; k++) s += A[(r + k) * EDGE + cc];
        V[i] = s;
    }
    __syncthreads();
    float best = -1e30f;
    int bidx = 1 << 30;
    for (int i = threadIdx.x; i < POOLED * POOLED; i += 256) {
        int r = i / POOLED, cc = i - r * POOLED;
        float s = 0.f;
#pragma unroll
        for (int k = 0; k < KPOOL; k++) s += V[r * EDGE + cc + k];
        if (s > best || (s == best && i < bidx)) { best = s; bidx = i; }
    }
    bv[threadIdx.x] = best;
    bi[threadIdx.x] = bidx;
    __syncthreads();
    for (int off = 128; off; off >>= 1) {
        if (threadIdx.x < off) {
            float ov = bv[threadIdx.x + off];
            int oi = bi[threadIdx.x + off];
            if (ov > bv[threadIdx.x] || (ov == bv[threadIdx.x] && oi < bi[threadIdx.x])) {
                bv[threadIdx.x] = ov;
                bi[threadIdx.x] = oi;
            }
        }
        __syncthreads();
    }
    if (threadIdx.x == 0) rc[bh] = bi[0];
}

// ---------------------------------------------------------------------------
// K4: gather region @ W_up, pixel-shuffle, write bf16 X [b][p2][h*64+d']
// ---------------------------------------------------------------------------
__global__ __launch_bounds__(256) void k_up(const float* __restrict__ img,
                                            const float* __restrict__ Wup,
                                            const int* __restrict__ rc,
                                            short* __restrict__ Xb) {
    __shared__ float R[64 * 64];
    int bh = blockIdx.x >> 2, pb = blockIdx.x & 3;
    int b = bh / NH, h = bh - b * NH;
    int idx = rc[bh];
    int r0 = idx / POOLED, c0 = idx - r0 * POOLED;

    for (int i = threadIdx.x; i < 4096; i += 256) {
        int pos = i >> 6, d = i & 63;
        int gi = r0 + pb * 4 + (pos >> 4);
        int gj = c0 + (pos & 15);
        R[i] = img[((size_t)b * SS + gi * EDGE + gj) * HID + h * DD + d];
    }
    __syncthreads();

    int oc = threadIdx.x;
    float w[64];
#pragma unroll
    for (int d = 0; d < 64; d++) w[d] = Wup[d * 256 + oc];
    int a = oc >> 7, bbit = (oc >> 6) & 1, dp = oc & 63;

    for (int pos = 0; pos < 64; pos++) {
        const float* rp = &R[pos * 64];
        float acc = 0.f;
#pragma unroll
        for (int d = 0; d < 64; d++) acc += rp[d] * w[d];
        int i16 = pb * 4 + (pos >> 4), j16 = pos & 15;
        int p2 = (2 * i16 + a) * EDGE + (2 * j16 + bbit);
        Xb[((size_t)b * SS + p2) * HID + h * DD + dp] = f2bf(acc);
    }
}

// ---------------------------------------------------------------------------
// K5: out = img + gelu(X @ W_in)   (bf16 MFMA, M=8192 N=768 K=768)
// grid: 64 m-blocks x 12 n-blocks; wave = 32m x 64n
// ---------------------------------------------------------------------------
__global__ __launch_bounds__(256) void k_out(const short* __restrict__ Xb,
                                             const short* __restrict__ Wt,
                                             const float* __restrict__ img,
                                             float* __restrict__ out) {
    int mblk = blockIdx.x & 63, nblk = blockIdx.x >> 6;
    int wave = threadIdx.x >> 6, lane = threadIdx.x & 63;
    int quad = lane >> 4, c = lane & 15;
    int m0 = mblk * 128 + wave * 32;
    int n0 = nblk * 64;

    f32x4 acc[2][4];
#pragma unroll
    for (int t = 0; t < 2; t++)
#pragma unroll
        for (int u = 0; u < 4; u++) acc[t][u] = (f32x4){0.f, 0.f, 0.f, 0.f};

    for (int k0 = 0; k0 < HID; k0 += 32) {
        bf16x8 a[2], bfr[4];
#pragma unroll
        for (int t = 0; t < 2; t++)
            a[t] = *(const bf16x8*)(Xb + (size_t)(m0 + t * 16 + c) * HID + k0 + quad * 8);
#pragma unroll
        for (int u = 0; u < 4; u++)
            bfr[u] = *(const bf16x8*)(Wt + (size_t)(n0 + u * 16 + c) * HID + k0 + quad * 8);
#pragma unroll
        for (int t = 0; t < 2; t++)
#pragma unroll
            for (int u = 0; u < 4; u++)
                acc[t][u] = MFMA16(a[t], bfr[u], acc[t][u]);
    }
#pragma unroll
    for (int t = 0; t < 2; t++) {
#pragma unroll
        for (int u = 0; u < 4; u++) {
#pragma unroll
            for (int r = 0; r < 4; r++) {
                int row = m0 + t * 16 + quad * 4 + r;
                int col = n0 + u * 16 + c;
                float x = acc[t][u][r];
                float g = 0.5f * x * (1.f + erff(x * 0.70710678118654752f));
                size_t o = (size_t)row * HID + col;
                out[o] = img[o] + g;
            }
        }
    }
}

// ---------------------------------------------------------------------------
// launch
// ---------------------------------------------------------------------------
extern "C" void kernel_launch(void* const* d_in, const int* in_sizes, int n_in,
                              void* d_out, int out_size, void* d_ws, size_t ws_size,
                              hipStream_t stream) {
    const float* img = (const float*)d_in[0];   // [8,1024,768]
    const float* txt = (const float*)d_in[1];   // [8,2048,768]
    const float* Win = (const float*)d_in[2];   // [768,768]
    const float* Wup = (const float*)d_in[3];   // [64,256]
    float* out = (float*)d_out;

    char* w = (char*)d_ws;
    short* Qs    = (short*)(w);                         // 96*2048*128*2 = 50331648
    short* Ks    = (short*)(w + 50331648);              // 96*1024*128*2 = 25165824
    short* Wt    = (short*)(w + 75497472);              // 768*768*2     = 1179648
    float* Lsum  = (float*)(w + 76677120);              // 96*2048*4     = 786432
    float* iattn = (float*)(w + 77463552);              // 96*1024*4     = 393216
    int*   rc    = (int*)(w + 77856768);                // 96*4
    short* Xb    = (short*)(w);                         // aliases Qs (dead after k_attnacc)

    k_castq<<<dim3(49152), dim3(256), 0, stream>>>(txt, Qs);
    k_castk<<<dim3(24576), dim3(256), 0, stream>>>(img, Ks);
    k_castw<<<dim3(144), dim3(256), 0, stream>>>(Win, Wt);
    hipMemsetAsync(iattn, 0, (size_t)BH * SS * sizeof(float), stream);
    k_lsum<<<dim3(1536), dim3(256), 0, stream>>>(Qs, Ks, Lsum);
    k_attnacc<<<dim3(1536), dim3(256), 0, stream>>>(Qs, Ks, Lsum, iattn);
    k_pool<<<dim3(96), dim3(256), 0, stream>>>(iattn, rc);
    k_up<<<dim3(384), dim3(256), 0, stream>>>(img, Wup, rc, Xb);
    k_out<<<dim3(768), dim3(256), 0, stream>>>(Xb, Wt, img, out);
}

// Round 6
// 356.728 us; speedup vs baseline: 1.8393x; 1.8393x over previous
//
#include <hip/hip_runtime.h>
#include <cstdint>
#include <cstddef>

// ---------------------------------------------------------------------------
// Problem constants
// ---------------------------------------------------------------------------
#define BB    8      // batch
#define NH    12     // heads
#define BH    96     // BB*NH
#define SS    1024   // image tokens (32x32)
#define QQ    2048   // text tokens
#define DD    64     // head dim
#define HID   768
#define EDGE  32
#define KPOOL 16
#define POOLED 17

typedef short bf16x8 __attribute__((ext_vector_type(8)));
typedef float f32x4  __attribute__((ext_vector_type(4)));

#define MFMA16(a, b, c) __builtin_amdgcn_mfma_f32_16x16x32_bf16((a), (b), (c), 0, 0, 0)

// scores in base-2: Q pre-scaled by log2(e)/8 so exp(s/8) == exp2(score2)
#define QSCALE 0.18033688011112042f

#if __has_builtin(__builtin_amdgcn_exp2f)
#define EXP2(x) __builtin_amdgcn_exp2f(x)
#else
#define EXP2(x) exp2f(x)
#endif

__device__ __forceinline__ short f2bf(float x) {
    unsigned u = __builtin_bit_cast(unsigned, x);
    u = u + 0x7fffu + ((u >> 16) & 1u);          // RNE
    return (short)(u >> 16);
}
__device__ __forceinline__ float bf2f(short h) {
    unsigned u = ((unsigned)(unsigned short)h) << 16;
    return __builtin_bit_cast(float, u);
}

// ---------------------------------------------------------------------------
// Fragment-order layout for Qs/Ks:
//   rows grouped by 16 (group g, row-in-group c). Per group: 2048 shorts =
//   4 chunks of 512: ch0=hi,k[0:32) ch1=hi,k[32:64) ch2=lo,k[0:32) ch3=lo,k[32:64)
//   chunk internal: [quad(4)][c(16)][j(8)]  -> frag read = base + lane*8 shorts
// ---------------------------------------------------------------------------

// K0a: cast text -> Qs fragment-order (scaled by QSCALE)
__global__ __launch_bounds__(256) void k_castq(const float* __restrict__ txt,
                                               short* __restrict__ Qs) {
    int i = blockIdx.x * 256 + threadIdx.x;
    int quad = i & 3, kh = (i >> 2) & 1;
    int row = i >> 3;                    // bh*2048 + q
    int c = row & 15, g = row >> 4;
    int q = row & 2047, bh = row >> 11;
    int b = bh / NH, h = bh - b * NH;
    const float* sp = txt + ((size_t)b * QQ + q) * HID + h * DD + kh * 32 + quad * 8;
    bf16x8 vh, vl;
#pragma unroll
    for (int j = 0; j < 8; j++) {
        float x = sp[j] * QSCALE;
        short hi = f2bf(x);
        vh[j] = hi;
        vl[j] = f2bf(x - bf2f(hi));
    }
    short* dp = Qs + (size_t)g * 2048 + kh * 512 + quad * 128 + c * 8;
    *(bf16x8*)dp = vh;
    *(bf16x8*)(dp + 1024) = vl;
}

// K0b: cast image -> Ks fragment-order (unscaled)
__global__ __launch_bounds__(256) void k_castk(const float* __restrict__ img,
                                               short* __restrict__ Ks) {
    int i = blockIdx.x * 256 + threadIdx.x;
    int quad = i & 3, kh = (i >> 2) & 1;
    int row = i >> 3;                    // bh*1024 + s
    int c = row & 15, g = row >> 4;
    int s = row & 1023, bh = row >> 10;
    int b = bh / NH, h = bh - b * NH;
    const float* sp = img + ((size_t)b * SS + s) * HID + h * DD + kh * 32 + quad * 8;
    bf16x8 vh, vl;
#pragma unroll
    for (int j = 0; j < 8; j++) {
        float x = sp[j];
        short hi = f2bf(x);
        vh[j] = hi;
        vl[j] = f2bf(x - bf2f(hi));
    }
    short* dp = Ks + (size_t)g * 2048 + kh * 512 + quad * 128 + c * 8;
    *(bf16x8*)dp = vh;
    *(bf16x8*)(dp + 1024) = vl;
}

// K0c: W_in [k][n] -> transposed bf16 [n][k], LDS tile
__global__ __launch_bounds__(256) void k_castw(const float* __restrict__ W,
                                               short* __restrict__ Wt) {
    __shared__ float T[64][65];
    int bx = blockIdx.x % 12, by = blockIdx.x / 12;
    for (int i = threadIdx.x; i < 4096; i += 256) {
        int r = i >> 6, cc = i & 63;
        T[r][cc] = W[(size_t)(by * 64 + r) * HID + bx * 64 + cc];
    }
    __syncthreads();
    for (int i = threadIdx.x; i < 4096; i += 256) {
        int r = i >> 6, cc = i & 63;
        Wt[(size_t)(bx * 64 + r) * HID + by * 64 + cc] = f2bf(T[cc][r]);
    }
}

// ---------------------------------------------------------------------------
// K1: Lsum[bh][q] = sum_s exp2(score2)
// grid: qblk(8) x bh(96). Block: 256 q rows; wave w owns 64 q (4 groups),
// streams ALL 1024 s via LDS tiles (64 s = 8192 shorts, double-buffered,
// register-staged ds_write_b128 — no global_load_lds). Single writer.
// ---------------------------------------------------------------------------
__global__ __launch_bounds__(256, 2) void k_lsum(const short* __restrict__ Qs,
                                                 const short* __restrict__ Ks,
                                                 float* __restrict__ Lsum) {
    __shared__ short Kt[2][8192];
    int bh = blockIdx.x % BH;
    int qblk = blockIdx.x / BH;          // [0,8)
    int tid = threadIdx.x;
    int w = tid >> 6, lane = tid & 63;
    int quad = lane >> 4, c = lane & 15;

    bf16x8 ah0[4], ah1[4], al0[4], al1[4];
    const short* qbase = Qs + (size_t)bh * QQ * 128;
#pragma unroll
    for (int t = 0; t < 4; t++) {
        const short* ap = qbase + (size_t)(qblk * 16 + w * 4 + t) * 2048 + lane * 8;
        ah0[t] = *(const bf16x8*)(ap);
        ah1[t] = *(const bf16x8*)(ap + 512);
        al0[t] = *(const bf16x8*)(ap + 1024);
        al1[t] = *(const bf16x8*)(ap + 1536);
    }
    f32x4 lacc[4];
#pragma unroll
    for (int t = 0; t < 4; t++) lacc[t] = (f32x4){0.f, 0.f, 0.f, 0.f};

    const short* kbase = Ks + (size_t)bh * SS * 128;
    // stage tile 0 into registers (identity copy: Kt[buf][x] = tile[x])
    bf16x8 st[4];
#pragma unroll
    for (int j = 0; j < 4; j++)
        st[j] = *(const bf16x8*)(kbase + (size_t)j * 2048 + tid * 8);

    for (int t1 = 0; t1 < 16; t1++) {
        int buf = t1 & 1;
#pragma unroll
        for (int j = 0; j < 4; j++)
            *(bf16x8*)(&Kt[buf][j * 2048 + tid * 8]) = st[j];
        if (t1 + 1 < 16) {
#pragma unroll
            for (int j = 0; j < 4; j++)
                st[j] = *(const bf16x8*)(kbase + (size_t)(t1 + 1) * 8192 + j * 2048 + tid * 8);
        }
        __syncthreads();                 // writes to buf visible; buf^1 free next iter
#pragma unroll
        for (int g = 0; g < 4; g++) {    // every wave consumes the whole tile
            const short* kp = &Kt[buf][g * 2048 + lane * 8];
            bf16x8 kb0 = *(const bf16x8*)(kp);
            bf16x8 kb1 = *(const bf16x8*)(kp + 512);
            bf16x8 kb2 = *(const bf16x8*)(kp + 1024);
            bf16x8 kb3 = *(const bf16x8*)(kp + 1536);
#pragma unroll
            for (int t = 0; t < 4; t++) {
                f32x4 acc = (f32x4){0.f, 0.f, 0.f, 0.f};
                acc = MFMA16(ah0[t], kb0, acc);
                acc = MFMA16(ah1[t], kb1, acc);
                acc = MFMA16(al0[t], kb0, acc);
                acc = MFMA16(al1[t], kb1, acc);
                acc = MFMA16(ah0[t], kb2, acc);
                acc = MFMA16(ah1[t], kb3, acc);
#pragma unroll
                for (int r = 0; r < 4; r++) lacc[t][r] += EXP2(acc[r]);
            }
        }
    }
#pragma unroll
    for (int t = 0; t < 4; t++) {
#pragma unroll
        for (int r = 0; r < 4; r++) {
            float v = lacc[t][r];
            v += __shfl_xor(v, 1);
            v += __shfl_xor(v, 2);
            v += __shfl_xor(v, 4);
            v += __shfl_xor(v, 8);
            if (c == 0)
                Lsum[(size_t)bh * QQ + qblk * 256 + w * 64 + t * 16 + quad * 4 + r] = v;
        }
    }
}

// ---------------------------------------------------------------------------
// K2: iattn[bh][s] += sum_{q in half} exp2(score2) / Lsum[q]
// grid: (sblk(4) x qh(2)) x bh(96). Block: 256 s rows; wave owns 64 s,
// streams 1024 q (16 LDS tiles, register-staged dbuf). Two qh blocks
// combine via atomicAdd (2 contributors, order-independent result).
// ---------------------------------------------------------------------------
__global__ __launch_bounds__(256, 2) void k_attnacc(const short* __restrict__ Qs,
                                                    const short* __restrict__ Ks,
                                                    const float* __restrict__ Lsum,
                                                    float* __restrict__ iattn) {
    __shared__ short Qt[2][8192];
    int bh = blockIdx.x % BH;
    int rem = blockIdx.x / BH;           // [0,8)
    int sblk = rem >> 1, qh = rem & 1;
    int tid = threadIdx.x;
    int w = tid >> 6, lane = tid & 63;
    int quad = lane >> 4, c = lane & 15;

    bf16x8 ah0[4], ah1[4], al0[4], al1[4];
    const short* kbase = Ks + (size_t)bh * SS * 128;
#pragma unroll
    for (int t = 0; t < 4; t++) {
        const short* ap = kbase + (size_t)(sblk * 16 + w * 4 + t) * 2048 + lane * 8;
        ah0[t] = *(const bf16x8*)(ap);
        ah1[t] = *(const bf16x8*)(ap + 512);
        al0[t] = *(const bf16x8*)(ap + 1024);
        al1[t] = *(const bf16x8*)(ap + 1536);
    }
    f32x4 racc[4];
#pragma unroll
    for (int t = 0; t < 4; t++) racc[t] = (f32x4){0.f, 0.f, 0.f, 0.f};

    const short* qbase = Qs + ((size_t)bh * QQ + qh * 1024) * 128;
    const float* lbase = Lsum + (size_t)bh * QQ + qh * 1024;

    bf16x8 st[4];
#pragma unroll
    for (int j = 0; j < 4; j++)
        st[j] = *(const bf16x8*)(qbase + (size_t)j * 2048 + tid * 8);

    for (int t2 = 0; t2 < 16; t2++) {
        int buf = t2 & 1;
#pragma unroll
        for (int j = 0; j < 4; j++)
            *(bf16x8*)(&Qt[buf][j * 2048 + tid * 8]) = st[j];
        if (t2 + 1 < 16) {
#pragma unroll
            for (int j = 0; j < 4; j++)
                st[j] = *(const bf16x8*)(qbase + (size_t)(t2 + 1) * 8192 + j * 2048 + tid * 8);
        }
        __syncthreads();
        float rl[4];
#pragma unroll
        for (int g = 0; g < 4; g++)
            rl[g] = __builtin_amdgcn_rcpf(lbase[t2 * 64 + g * 16 + c]);
#pragma unroll
        for (int g = 0; g < 4; g++) {
            const short* qp = &Qt[buf][g * 2048 + lane * 8];
            bf16x8 qb0 = *(const bf16x8*)(qp);
            bf16x8 qb1 = *(const bf16x8*)(qp + 512);
            bf16x8 qb2 = *(const bf16x8*)(qp + 1024);
            bf16x8 qb3 = *(const bf16x8*)(qp + 1536);
#pragma unroll
            for (int t = 0; t < 4; t++) {
                f32x4 acc = (f32x4){0.f, 0.f, 0.f, 0.f};
                acc = MFMA16(ah0[t], qb0, acc);
                acc = MFMA16(ah1[t], qb1, acc);
                acc = MFMA16(al0[t], qb0, acc);
                acc = MFMA16(al1[t], qb1, acc);
                acc = MFMA16(ah0[t], qb2, acc);
                acc = MFMA16(ah1[t], qb3, acc);
#pragma unroll
                for (int r = 0; r < 4; r++)
                    racc[t][r] = fmaf(EXP2(acc[r]), rl[g], racc[t][r]);
            }
        }
    }
#pragma unroll
    for (int t = 0; t < 4; t++) {
#pragma unroll
        for (int r = 0; r < 4; r++) {
            float v = racc[t][r];
            v += __shfl_xor(v, 1);
            v += __shfl_xor(v, 2);
            v += __shfl_xor(v, 4);
            v += __shfl_xor(v, 8);
            if (c == 0)
                atomicAdd(&iattn[(size_t)bh * SS + sblk * 256 + w * 64 + t * 16 + quad * 4 + r], v);
        }
    }
}

// ---------------------------------------------------------------------------
// K3: 16x16 sum-pool (valid) over 32x32 map, argmax (np first-max tiebreak)
// ---------------------------------------------------------------------------
__global__ __launch_bounds__(256) void k_pool(const float* __restrict__ iattn,
                                              int* __restrict__ rc) {
    __shared__ float A[1024];
    __shared__ float V[POOLED * EDGE];
    __shared__ float bv[256];
    __shared__ int bi[256];
    int bh = blockIdx.x;
    for (int i = threadIdx.x; i < 1024; i += 256) A[i] = iattn[(size_t)bh * SS + i];
    __syncthreads();
    for (int i = threadIdx.x; i < POOLED * EDGE; i += 256) {
        int r = i >> 5, cc = i & 31;
        float s = 0.f;
#pragma unroll
        for (int k = 0; k < KPOOL; k++) s += A[(r + k) * EDGE + cc];
        V[i] = s;
    }
    __syncthreads();
    float best = -1e30f;
    int bidx = 1 << 30;
    for (int i = threadIdx.x; i < POOLED * POOLED; i += 256) {
        int r = i / POOLED, cc = i - r * POOLED;
        float s = 0.f;
#pragma unroll
        for (int k = 0; k < KPOOL; k++) s += V[r * EDGE + cc + k];
        if (s > best || (s == best && i < bidx)) { best = s; bidx = i; }
    }
    bv[threadIdx.x] = best;
    bi[threadIdx.x] = bidx;
    __syncthreads();
    for (int off = 128; off; off >>= 1) {
        if (threadIdx.x < off) {
            float ov = bv[threadIdx.x + off];
            int oi = bi[threadIdx.x + off];
            if (ov > bv[threadIdx.x] || (ov == bv[threadIdx.x] && oi < bi[threadIdx.x])) {
                bv[threadIdx.x] = ov;
                bi[threadIdx.x] = oi;
            }
        }
        __syncthreads();
    }
    if (threadIdx.x == 0) rc[bh] = bi[0];
}

// ---------------------------------------------------------------------------
// K4: gather region @ W_up, pixel-shuffle, write bf16 X [b][p2][h*64+d']
// ---------------------------------------------------------------------------
__global__ __launch_bounds__(256) void k_up(const float* __restrict__ img,
                                            const float* __restrict__ Wup,
                                            const int* __restrict__ rc,
                                            short* __restrict__ Xb) {
    __shared__ float R[64 * 64];
    int bh = blockIdx.x >> 2, pb = blockIdx.x & 3;
    int b = bh / NH, h = bh - b * NH;
    int idx = rc[bh];
    int r0 = idx / POOLED, c0 = idx - r0 * POOLED;

    for (int i = threadIdx.x; i < 4096; i += 256) {
        int pos = i >> 6, d = i & 63;
        int gi = r0 + pb * 4 + (pos >> 4);
        int gj = c0 + (pos & 15);
        R[i] = img[((size_t)b * SS + gi * EDGE + gj) * HID + h * DD + d];
    }
    __syncthreads();

    int oc = threadIdx.x;
    float wv[64];
#pragma unroll
    for (int d = 0; d < 64; d++) wv[d] = Wup[d * 256 + oc];
    int a = oc >> 7, bbit = (oc >> 6) & 1, dp = oc & 63;

    for (int pos = 0; pos < 64; pos++) {
        const float* rp = &R[pos * 64];
        float acc = 0.f;
#pragma unroll
        for (int d = 0; d < 64; d++) acc += rp[d] * wv[d];
        int i16 = pb * 4 + (pos >> 4), j16 = pos & 15;
        int p2 = (2 * i16 + a) * EDGE + (2 * j16 + bbit);
        Xb[((size_t)b * SS + p2) * HID + h * DD + dp] = f2bf(acc);
    }
}

// ---------------------------------------------------------------------------
// K5: out = img + gelu(X @ W_in)   (bf16 MFMA, M=8192 N=768 K=768)
// grid: 32 m-blocks x 12 n-blocks; wave = 64m x 64n  (round-1 shape, passed)
// ---------------------------------------------------------------------------
__global__ __launch_bounds__(256) void k_out(const short* __restrict__ Xb,
                                             const short* __restrict__ Wt,
                                             const float* __restrict__ img,
                                             float* __restrict__ out) {
    int mblk = blockIdx.x & 31, nblk = blockIdx.x >> 5;
    int wave = threadIdx.x >> 6, lane = threadIdx.x & 63;
    int quad = lane >> 4, c = lane & 15;
    int m0 = mblk * 256 + wave * 64;
    int n0 = nblk * 64;

    f32x4 acc[4][4];
#pragma unroll
    for (int t = 0; t < 4; t++)
#pragma unroll
        for (int u = 0; u < 4; u++) acc[t][u] = (f32x4){0.f, 0.f, 0.f, 0.f};

    for (int k0 = 0; k0 < HID; k0 += 32) {
        bf16x8 a[4], bfr[4];
#pragma unroll
        for (int t = 0; t < 4; t++)
            a[t] = *(const bf16x8*)(Xb + (size_t)(m0 + t * 16 + c) * HID + k0 + quad * 8);
#pragma unroll
        for (int u = 0; u < 4; u++)
            bfr[u] = *(const bf16x8*)(Wt + (size_t)(n0 + u * 16 + c) * HID + k0 + quad * 8);
#pragma unroll
        for (int t = 0; t < 4; t++)
#pragma unroll
            for (int u = 0; u < 4; u++)
                acc[t][u] = MFMA16(a[t], bfr[u], acc[t][u]);
    }
#pragma unroll
    for (int t = 0; t < 4; t++) {
#pragma unroll
        for (int u = 0; u < 4; u++) {
#pragma unroll
            for (int r = 0; r < 4; r++) {
                int row = m0 + t * 16 + quad * 4 + r;
                int col = n0 + u * 16 + c;
                float x = acc[t][u][r];
                float g = 0.5f * x * (1.f + erff(x * 0.70710678118654752f));
                size_t o = (size_t)row * HID + col;
                out[o] = img[o] + g;
            }
        }
    }
}

// ---------------------------------------------------------------------------
// launch
// ---------------------------------------------------------------------------
extern "C" void kernel_launch(void* const* d_in, const int* in_sizes, int n_in,
                              void* d_out, int out_size, void* d_ws, size_t ws_size,
                              hipStream_t stream) {
    const float* img = (const float*)d_in[0];   // [8,1024,768]
    const float* txt = (const float*)d_in[1];   // [8,2048,768]
    const float* Win = (const float*)d_in[2];   // [768,768]
    const float* Wup = (const float*)d_in[3];   // [64,256]
    float* out = (float*)d_out;

    char* w = (char*)d_ws;
    short* Qs    = (short*)(w);                         // 96*2048*128*2 = 50331648
    short* Ks    = (short*)(w + 50331648);              // 96*1024*128*2 = 25165824
    short* Wt    = (short*)(w + 75497472);              // 768*768*2     = 1179648
    float* Lsum  = (float*)(w + 76677120);              // 96*2048*4     = 786432
    float* iattn = (float*)(w + 77463552);              // 96*1024*4     = 393216
    int*   rc    = (int*)(w + 77856768);                // 96*4
    short* Xb    = (short*)(w);                         // aliases Qs (dead after k_attnacc)

    k_castq<<<dim3(6144), dim3(256), 0, stream>>>(txt, Qs);
    k_castk<<<dim3(3072), dim3(256), 0, stream>>>(img, Ks);
    k_castw<<<dim3(144), dim3(256), 0, stream>>>(Win, Wt);
    hipMemsetAsync(iattn, 0, (size_t)BH * SS * sizeof(float), stream);
    k_lsum<<<dim3(768), dim3(256), 0, stream>>>(Qs, Ks, Lsum);
    k_attnacc<<<dim3(768), dim3(256), 0, stream>>>(Qs, Ks, Lsum, iattn);
    k_pool<<<dim3(96), dim3(256), 0, stream>>>(iattn, rc);
    k_up<<<dim3(384), dim3(256), 0, stream>>>(img, Wup, rc, Xb);
    k_out<<<dim3(384), dim3(256), 0, stream>>>(Xb, Wt, img, out);
}

// Round 7
// 341.834 us; speedup vs baseline: 1.9194x; 1.0436x over previous
//
#include <hip/hip_runtime.h>
#include <cstdint>
#include <cstddef>

// ---------------------------------------------------------------------------
// Problem constants
// ---------------------------------------------------------------------------
#define BB    8      // batch
#define NH    12     // heads
#define BH    96     // BB*NH
#define SS    1024   // image tokens (32x32)
#define QQ    2048   // text tokens
#define DD    64     // head dim
#define HID   768
#define EDGE  32
#define KPOOL 16
#define POOLED 17

typedef short bf16x8 __attribute__((ext_vector_type(8)));
typedef float f32x4  __attribute__((ext_vector_type(4)));

#define MFMA16(a, b, c) __builtin_amdgcn_mfma_f32_16x16x32_bf16((a), (b), (c), 0, 0, 0)

// scores in base-2: Q pre-scaled by log2(e)/8 so exp(s/8) == exp2(score2)
#define QSCALE 0.18033688011112042f

#if __has_builtin(__builtin_amdgcn_exp2f)
#define EXP2(x) __builtin_amdgcn_exp2f(x)
#else
#define EXP2(x) exp2f(x)
#endif

__device__ __forceinline__ short f2bf(float x) {
    unsigned u = __builtin_bit_cast(unsigned, x);
    u = u + 0x7fffu + ((u >> 16) & 1u);          // RNE
    return (short)(u >> 16);
}
__device__ __forceinline__ float bf2f(short h) {
    unsigned u = ((unsigned)(unsigned short)h) << 16;
    return __builtin_bit_cast(float, u);
}

// ---------------------------------------------------------------------------
// Fragment-order layout for Qs/Ks:
//   rows grouped by 16 (group g, row-in-group c). Per group: 2048 shorts =
//   4 chunks of 512: ch0=hi,k[0:32) ch1=hi,k[32:64) ch2=lo,k[0:32) ch3=lo,k[32:64)
//   chunk internal: [quad(4)][c(16)][j(8)]  -> frag read = base + lane*8 shorts
// ---------------------------------------------------------------------------

// K0a: cast text -> Qs fragment-order (scaled by QSCALE)
__global__ __launch_bounds__(256) void k_castq(const float* __restrict__ txt,
                                               short* __restrict__ Qs) {
    int i = blockIdx.x * 256 + threadIdx.x;
    int quad = i & 3, kh = (i >> 2) & 1;
    int row = i >> 3;                    // bh*2048 + q
    int c = row & 15, g = row >> 4;
    int q = row & 2047, bh = row >> 11;
    int b = bh / NH, h = bh - b * NH;
    const float* sp = txt + ((size_t)b * QQ + q) * HID + h * DD + kh * 32 + quad * 8;
    bf16x8 vh, vl;
#pragma unroll
    for (int j = 0; j < 8; j++) {
        float x = sp[j] * QSCALE;
        short hi = f2bf(x);
        vh[j] = hi;
        vl[j] = f2bf(x - bf2f(hi));
    }
    short* dp = Qs + (size_t)g * 2048 + kh * 512 + quad * 128 + c * 8;
    *(bf16x8*)dp = vh;
    *(bf16x8*)(dp + 1024) = vl;
}

// K0b: cast image -> Ks fragment-order (unscaled)
__global__ __launch_bounds__(256) void k_castk(const float* __restrict__ img,
                                               short* __restrict__ Ks) {
    int i = blockIdx.x * 256 + threadIdx.x;
    int quad = i & 3, kh = (i >> 2) & 1;
    int row = i >> 3;                    // bh*1024 + s
    int c = row & 15, g = row >> 4;
    int s = row & 1023, bh = row >> 10;
    int b = bh / NH, h = bh - b * NH;
    const float* sp = img + ((size_t)b * SS + s) * HID + h * DD + kh * 32 + quad * 8;
    bf16x8 vh, vl;
#pragma unroll
    for (int j = 0; j < 8; j++) {
        float x = sp[j];
        short hi = f2bf(x);
        vh[j] = hi;
        vl[j] = f2bf(x - bf2f(hi));
    }
    short* dp = Ks + (size_t)g * 2048 + kh * 512 + quad * 128 + c * 8;
    *(bf16x8*)dp = vh;
    *(bf16x8*)(dp + 1024) = vl;
}

// K0c: blocks 0..143: W_in [k][n] -> transposed bf16 Wt [n][k].
//      block 144: W_up [64][256] -> bf16 B-fragment order Wupb:
//      addr = (n>>4)*1024 + (k>>5)*512 + ((k>>3)&3)*128 + (n&15)*8 + (k&7)
__global__ __launch_bounds__(256) void k_castw(const float* __restrict__ W,
                                               const float* __restrict__ Wup,
                                               short* __restrict__ Wt,
                                               short* __restrict__ Wupb) {
    if (blockIdx.x == 144) {
        for (int i = threadIdx.x; i < 16384; i += 256) {
            int k = i >> 8, n = i & 255;
            int addr = (n >> 4) * 1024 + (k >> 5) * 512 + ((k >> 3) & 3) * 128
                     + (n & 15) * 8 + (k & 7);
            Wupb[addr] = f2bf(Wup[k * 256 + n]);
        }
        return;
    }
    __shared__ float T[64][65];
    int bx = blockIdx.x % 12, by = blockIdx.x / 12;
    for (int i = threadIdx.x; i < 4096; i += 256) {
        int r = i >> 6, cc = i & 63;
        T[r][cc] = W[(size_t)(by * 64 + r) * HID + bx * 64 + cc];
    }
    __syncthreads();
    for (int i = threadIdx.x; i < 4096; i += 256) {
        int r = i >> 6, cc = i & 63;
        Wt[(size_t)(bx * 64 + r) * HID + by * 64 + cc] = f2bf(T[cc][r]);
    }
}

// ---------------------------------------------------------------------------
// K1: Lsum[bh][q] = sum_s exp2(score2)   (UNCHANGED from round 6 — proven)
// ---------------------------------------------------------------------------
__global__ __launch_bounds__(256, 2) void k_lsum(const short* __restrict__ Qs,
                                                 const short* __restrict__ Ks,
                                                 float* __restrict__ Lsum) {
    __shared__ short Kt[2][8192];
    int bh = blockIdx.x % BH;
    int qblk = blockIdx.x / BH;          // [0,8)
    int tid = threadIdx.x;
    int w = tid >> 6, lane = tid & 63;
    int quad = lane >> 4, c = lane & 15;

    bf16x8 ah0[4], ah1[4], al0[4], al1[4];
    const short* qbase = Qs + (size_t)bh * QQ * 128;
#pragma unroll
    for (int t = 0; t < 4; t++) {
        const short* ap = qbase + (size_t)(qblk * 16 + w * 4 + t) * 2048 + lane * 8;
        ah0[t] = *(const bf16x8*)(ap);
        ah1[t] = *(const bf16x8*)(ap + 512);
        al0[t] = *(const bf16x8*)(ap + 1024);
        al1[t] = *(const bf16x8*)(ap + 1536);
    }
    f32x4 lacc[4];
#pragma unroll
    for (int t = 0; t < 4; t++) lacc[t] = (f32x4){0.f, 0.f, 0.f, 0.f};

    const short* kbase = Ks + (size_t)bh * SS * 128;
    bf16x8 st[4];
#pragma unroll
    for (int j = 0; j < 4; j++)
        st[j] = *(const bf16x8*)(kbase + (size_t)j * 2048 + tid * 8);

    for (int t1 = 0; t1 < 16; t1++) {
        int buf = t1 & 1;
#pragma unroll
        for (int j = 0; j < 4; j++)
            *(bf16x8*)(&Kt[buf][j * 2048 + tid * 8]) = st[j];
        if (t1 + 1 < 16) {
#pragma unroll
            for (int j = 0; j < 4; j++)
                st[j] = *(const bf16x8*)(kbase + (size_t)(t1 + 1) * 8192 + j * 2048 + tid * 8);
        }
        __syncthreads();
#pragma unroll
        for (int g = 0; g < 4; g++) {
            const short* kp = &Kt[buf][g * 2048 + lane * 8];
            bf16x8 kb0 = *(const bf16x8*)(kp);
            bf16x8 kb1 = *(const bf16x8*)(kp + 512);
            bf16x8 kb2 = *(const bf16x8*)(kp + 1024);
            bf16x8 kb3 = *(const bf16x8*)(kp + 1536);
#pragma unroll
            for (int t = 0; t < 4; t++) {
                f32x4 acc = (f32x4){0.f, 0.f, 0.f, 0.f};
                acc = MFMA16(ah0[t], kb0, acc);
                acc = MFMA16(ah1[t], kb1, acc);
                acc = MFMA16(al0[t], kb0, acc);
                acc = MFMA16(al1[t], kb1, acc);
                acc = MFMA16(ah0[t], kb2, acc);
                acc = MFMA16(ah1[t], kb3, acc);
#pragma unroll
                for (int r = 0; r < 4; r++) lacc[t][r] += EXP2(acc[r]);
            }
        }
    }
#pragma unroll
    for (int t = 0; t < 4; t++) {
#pragma unroll
        for (int r = 0; r < 4; r++) {
            float v = lacc[t][r];
            v += __shfl_xor(v, 1);
            v += __shfl_xor(v, 2);
            v += __shfl_xor(v, 4);
            v += __shfl_xor(v, 8);
            if (c == 0)
                Lsum[(size_t)bh * QQ + qblk * 256 + w * 64 + t * 16 + quad * 4 + r] = v;
        }
    }
}

// ---------------------------------------------------------------------------
// K2: iattn[bh][s] += sum_{q half} exp2(score2)/Lsum[q]  (UNCHANGED — proven)
// ---------------------------------------------------------------------------
__global__ __launch_bounds__(256, 2) void k_attnacc(const short* __restrict__ Qs,
                                                    const short* __restrict__ Ks,
                                                    const float* __restrict__ Lsum,
                                                    float* __restrict__ iattn) {
    __shared__ short Qt[2][8192];
    int bh = blockIdx.x % BH;
    int rem = blockIdx.x / BH;           // [0,8)
    int sblk = rem >> 1, qh = rem & 1;
    int tid = threadIdx.x;
    int w = tid >> 6, lane = tid & 63;
    int quad = lane >> 4, c = lane & 15;

    bf16x8 ah0[4], ah1[4], al0[4], al1[4];
    const short* kbase = Ks + (size_t)bh * SS * 128;
#pragma unroll
    for (int t = 0; t < 4; t++) {
        const short* ap = kbase + (size_t)(sblk * 16 + w * 4 + t) * 2048 + lane * 8;
        ah0[t] = *(const bf16x8*)(ap);
        ah1[t] = *(const bf16x8*)(ap + 512);
        al0[t] = *(const bf16x8*)(ap + 1024);
        al1[t] = *(const bf16x8*)(ap + 1536);
    }
    f32x4 racc[4];
#pragma unroll
    for (int t = 0; t < 4; t++) racc[t] = (f32x4){0.f, 0.f, 0.f, 0.f};

    const short* qbase = Qs + ((size_t)bh * QQ + qh * 1024) * 128;
    const float* lbase = Lsum + (size_t)bh * QQ + qh * 1024;

    bf16x8 st[4];
#pragma unroll
    for (int j = 0; j < 4; j++)
        st[j] = *(const bf16x8*)(qbase + (size_t)j * 2048 + tid * 8);

    for (int t2 = 0; t2 < 16; t2++) {
        int buf = t2 & 1;
#pragma unroll
        for (int j = 0; j < 4; j++)
            *(bf16x8*)(&Qt[buf][j * 2048 + tid * 8]) = st[j];
        if (t2 + 1 < 16) {
#pragma unroll
            for (int j = 0; j < 4; j++)
                st[j] = *(const bf16x8*)(qbase + (size_t)(t2 + 1) * 8192 + j * 2048 + tid * 8);
        }
        __syncthreads();
        float rl[4];
#pragma unroll
        for (int g = 0; g < 4; g++)
            rl[g] = __builtin_amdgcn_rcpf(lbase[t2 * 64 + g * 16 + c]);
#pragma unroll
        for (int g = 0; g < 4; g++) {
            const short* qp = &Qt[buf][g * 2048 + lane * 8];
            bf16x8 qb0 = *(const bf16x8*)(qp);
            bf16x8 qb1 = *(const bf16x8*)(qp + 512);
            bf16x8 qb2 = *(const bf16x8*)(qp + 1024);
            bf16x8 qb3 = *(const bf16x8*)(qp + 1536);
#pragma unroll
            for (int t = 0; t < 4; t++) {
                f32x4 acc = (f32x4){0.f, 0.f, 0.f, 0.f};
                acc = MFMA16(ah0[t], qb0, acc);
                acc = MFMA16(ah1[t], qb1, acc);
                acc = MFMA16(al0[t], qb0, acc);
                acc = MFMA16(al1[t], qb1, acc);
                acc = MFMA16(ah0[t], qb2, acc);
                acc = MFMA16(ah1[t], qb3, acc);
#pragma unroll
                for (int r = 0; r < 4; r++)
                    racc[t][r] = fmaf(EXP2(acc[r]), rl[g], racc[t][r]);
            }
        }
    }
#pragma unroll
    for (int t = 0; t < 4; t++) {
#pragma unroll
        for (int r = 0; r < 4; r++) {
            float v = racc[t][r];
            v += __shfl_xor(v, 1);
            v += __shfl_xor(v, 2);
            v += __shfl_xor(v, 4);
            v += __shfl_xor(v, 8);
            if (c == 0)
                atomicAdd(&iattn[(size_t)bh * SS + sblk * 256 + w * 64 + t * 16 + quad * 4 + r], v);
        }
    }
}

// ---------------------------------------------------------------------------
// K4: fused pool+argmax+region-gather+upsample GEMM (MFMA) + pixel-shuffle.
// grid: bh(96) x nq(4 oc-quarters). Block: pool argmax from iattn (redundant
// per nq — cheap), then region [256 pos x 64 d] staged bf16 A-frag order in
// LDS, W_up from Wupb B-frags, MFMA -> Xb bf16.
// ---------------------------------------------------------------------------
__global__ __launch_bounds__(256, 2) void k_up(const float* __restrict__ img,
                                               const float* __restrict__ iattn,
                                               const short* __restrict__ Wupb,
                                               short* __restrict__ Xb) {
    __shared__ short Reg[16384];         // 32 KB, aliased for pool phase
    float* F = (float*)Reg;
    float* Apool = F;                    // [1024]
    float* Vp = F + 1024;                // [544]
    float* bvp = F + 1568;               // [256]
    int*   bip = (int*)(F + 1824);       // [256]

    int bh = blockIdx.x >> 2, nq = blockIdx.x & 3;
    int b = bh / NH, h = bh - b * NH;
    int tid = threadIdx.x;
    int w = tid >> 6, lane = tid & 63;
    int quad = lane >> 4, c = lane & 15;

    // ---- pool + argmax (np first-max tiebreak) ----
    for (int i = tid; i < 1024; i += 256) Apool[i] = iattn[(size_t)bh * SS + i];
    __syncthreads();
    for (int i = tid; i < POOLED * EDGE; i += 256) {
        int r = i >> 5, cc = i & 31;
        float s = 0.f;
#pragma unroll
        for (int k = 0; k < KPOOL; k++) s += Apool[(r + k) * EDGE + cc];
        Vp[i] = s;
    }
    __syncthreads();
    float best = -1e30f;
    int bidx = 1 << 30;
    for (int i = tid; i < POOLED * POOLED; i += 256) {
        int r = i / POOLED, cc = i - r * POOLED;
        float s = 0.f;
#pragma unroll
        for (int k = 0; k < KPOOL; k++) s += Vp[r * EDGE + cc + k];
        if (s > best || (s == best && i < bidx)) { best = s; bidx = i; }
    }
    bvp[tid] = best;
    bip[tid] = bidx;
    __syncthreads();
    for (int off = 128; off; off >>= 1) {
        if (tid < off) {
            float ov = bvp[tid + off];
            int oi = bip[tid + off];
            if (ov > bvp[tid] || (ov == bvp[tid] && oi < bip[tid])) {
                bvp[tid] = ov;
                bip[tid] = oi;
            }
        }
        __syncthreads();
    }
    int widx = bip[0];
    __syncthreads();                     // all reads done before staging overwrites
    int r0 = widx / POOLED, c0 = widx - r0 * POOLED;

    // ---- stage region bf16 in A-fragment order ----
    // LDS addr for (pos,d): (pos>>4)*1024 + (d>>5)*512 + ((d>>3)&3)*128 + (pos&15)*8 + (d&7)
    for (int p = tid; p < 2048; p += 256) {
        int pos = p >> 3, sub = p & 7;   // sub -> d = sub*8..sub*8+7
        int gi = r0 + (pos >> 4), gj = c0 + (pos & 15);
        const float* sp = img + ((size_t)b * SS + gi * EDGE + gj) * HID + h * DD + sub * 8;
        bf16x8 v;
#pragma unroll
        for (int j = 0; j < 8; j++) v[j] = f2bf(sp[j]);
        *(bf16x8*)(&Reg[(pos >> 4) * 1024 + (sub >> 2) * 512 + (sub & 3) * 128 + (pos & 15) * 8]) = v;
    }
    __syncthreads();

    // ---- B-fragments (this block's 64 oc = 4 n-tiles) ----
    bf16x8 bu[4][2];
#pragma unroll
    for (int u = 0; u < 4; u++) {
#pragma unroll
        for (int kh = 0; kh < 2; kh++)
            bu[u][kh] = *(const bf16x8*)(Wupb + (nq * 4 + u) * 1024 + kh * 512 + lane * 8);
    }

    // ---- MFMA + pixel-shuffle epilogue ----
#pragma unroll
    for (int t = 0; t < 4; t++) {
        int g = w * 4 + t;               // pos group [0,16)
        bf16x8 a0 = *(const bf16x8*)(&Reg[g * 1024 + lane * 8]);
        bf16x8 a1 = *(const bf16x8*)(&Reg[g * 1024 + 512 + lane * 8]);
#pragma unroll
        for (int u = 0; u < 4; u++) {
            f32x4 acc = (f32x4){0.f, 0.f, 0.f, 0.f};
            acc = MFMA16(a0, bu[u][0], acc);
            acc = MFMA16(a1, bu[u][1], acc);
#pragma unroll
            for (int r = 0; r < 4; r++) {
                int pos = g * 16 + quad * 4 + r;
                int oc = nq * 64 + u * 16 + c;
                int i16 = pos >> 4, j16 = pos & 15;
                int a = oc >> 7, bbit = (oc >> 6) & 1, dp = oc & 63;
                int p2 = (2 * i16 + a) * EDGE + (2 * j16 + bbit);
                Xb[((size_t)b * SS + p2) * HID + h * DD + dp] = f2bf(acc[r]);
            }
        }
    }
}

// ---------------------------------------------------------------------------
// K5: out = img + gelu(X @ W_in)   (bf16 MFMA, M=8192 N=768 K=768)
// grid: 64 m-blocks x 12 n-blocks (768); wave = 32m x 64n
// ---------------------------------------------------------------------------
__global__ __launch_bounds__(256, 2) void k_out(const short* __restrict__ Xb,
                                                const short* __restrict__ Wt,
                                                const float* __restrict__ img,
                                                float* __restrict__ out) {
    int mblk = blockIdx.x & 63, nblk = blockIdx.x >> 6;
    int wave = threadIdx.x >> 6, lane = threadIdx.x & 63;
    int quad = lane >> 4, c = lane & 15;
    int m0 = mblk * 128 + wave * 32;
    int n0 = nblk * 64;

    f32x4 acc[2][4];
#pragma unroll
    for (int t = 0; t < 2; t++)
#pragma unroll
        for (int u = 0; u < 4; u++) acc[t][u] = (f32x4){0.f, 0.f, 0.f, 0.f};

    for (int k0 = 0; k0 < HID; k0 += 32) {
        bf16x8 a[2], bfr[4];
#pragma unroll
        for (int t = 0; t < 2; t++)
            a[t] = *(const bf16x8*)(Xb + (size_t)(m0 + t * 16 + c) * HID + k0 + quad * 8);
#pragma unroll
        for (int u = 0; u < 4; u++)
            bfr[u] = *(const bf16x8*)(Wt + (size_t)(n0 + u * 16 + c) * HID + k0 + quad * 8);
#pragma unroll
        for (int t = 0; t < 2; t++)
#pragma unroll
            for (int u = 0; u < 4; u++)
                acc[t][u] = MFMA16(a[t], bfr[u], acc[t][u]);
    }
#pragma unroll
    for (int t = 0; t < 2; t++) {
#pragma unroll
        for (int u = 0; u < 4; u++) {
#pragma unroll
            for (int r = 0; r < 4; r++) {
                int row = m0 + t * 16 + quad * 4 + r;
                int col = n0 + u * 16 + c;
                float x = acc[t][u][r];
                float g = 0.5f * x * (1.f + erff(x * 0.70710678118654752f));
                size_t o = (size_t)row * HID + col;
                out[o] = img[o] + g;
            }
        }
    }
}

// ---------------------------------------------------------------------------
// launch
// ---------------------------------------------------------------------------
extern "C" void kernel_launch(void* const* d_in, const int* in_sizes, int n_in,
                              void* d_out, int out_size, void* d_ws, size_t ws_size,
                              hipStream_t stream) {
    const float* img = (const float*)d_in[0];   // [8,1024,768]
    const float* txt = (const float*)d_in[1];   // [8,2048,768]
    const float* Win = (const float*)d_in[2];   // [768,768]
    const float* Wup = (const float*)d_in[3];   // [64,256]
    float* out = (float*)d_out;

    char* w = (char*)d_ws;
    short* Qs    = (short*)(w);                         // 96*2048*128*2 = 50331648
    short* Ks    = (short*)(w + 50331648);              // 96*1024*128*2 = 25165824
    short* Wt    = (short*)(w + 75497472);              // 768*768*2     = 1179648
    float* Lsum  = (float*)(w + 76677120);              // 96*2048*4     = 786432
    float* iattn = (float*)(w + 77463552);              // 96*1024*4     = 393216
    short* Wupb  = (short*)(w + 77856768);              // 16384*2       = 32768
    short* Xb    = (short*)(w);                         // aliases Qs (dead after k_attnacc)

    k_castq<<<dim3(6144), dim3(256), 0, stream>>>(txt, Qs);
    k_castk<<<dim3(3072), dim3(256), 0, stream>>>(img, Ks);
    k_castw<<<dim3(145), dim3(256), 0, stream>>>(Win, Wup, Wt, Wupb);
    hipMemsetAsync(iattn, 0, (size_t)BH * SS * sizeof(float), stream);
    k_lsum<<<dim3(768), dim3(256), 0, stream>>>(Qs, Ks, Lsum);
    k_attnacc<<<dim3(768), dim3(256), 0, stream>>>(Qs, Ks, Lsum, iattn);
    k_up<<<dim3(384), dim3(256), 0, stream>>>(img, iattn, Wupb, Xb);
    k_out<<<dim3(768), dim3(256), 0, stream>>>(Xb, Wt, img, out);
}